// Round 7
// baseline (26.825 us; speedup 1.0000x reference)
//
#include <hip/hip_runtime.h>

typedef __bf16 bf16x8 __attribute__((ext_vector_type(8)));
typedef float f32x4 __attribute__((ext_vector_type(4)));
typedef float f32x2 __attribute__((ext_vector_type(2)));

// coords_o = sum_{t in {I,cos,sin}^4} C_o[t] * prod_q f_{t_q}(a_q) + c_o
// Packed: g_C01[2t+{0,1}] = C_{0,1}[t]; g_C2[t] = C_2[t]; g_off = offsets.
__device__ __attribute__((aligned(16))) float g_C01[162];
__device__ float g_C2[81];
__device__ float g_off[3];

#define NQ 4
#define NLAYERS 2

__global__ __launch_bounds__(256) void precompute_kernel(
    const float* __restrict__ qw,
    const float* __restrict__ Wq2c,
    const float* __restrict__ bq2c,
    const float* __restrict__ Wout,
    const float* __restrict__ bout) {
  __shared__ float Ucoef[8][8];  // [gate][u00r,u00i,u01r,u01i,u10r,u10i,u11r,u11i]
  __shared__ float Ur[16][16];   // Ur[amp][col] = Re <amp|U|col>
  __shared__ float Ui[16][16];
  __shared__ float A[4][16][16];
  __shared__ float Wc[3][4];
  const int tid = threadIdx.x;

  // phase 0: all 8 gates' 2x2 unitary entries, 64 threads in parallel
  if (tid < 64) {
    const int gate = tid >> 3, comp = tid & 7;
    const float phi   = qw[gate * 3 + 0];
    const float theta = qw[gate * 3 + 1];
    const float omega = qw[gate * 3 + 2];
    const float cs = (comp == 2 || comp == 3 || comp == 4 || comp == 5)
                         ? __sinf(0.5f * theta)    // st
                         : __cosf(0.5f * theta);   // ct
    const float ang = (comp == 2 || comp == 3 || comp == 4 || comp == 5)
                          ? -0.5f * (phi - omega)  // am
                          : -0.5f * (phi + omega); // ap
    const float tr = ((comp & 1) == 0) ? __cosf(ang) : __sinf(ang);
    // signs: u01r = -emr*st (comp2), u11i = -epi*ct (comp7)
    const float sgn = (comp == 2 || comp == 7) ? -1.f : 1.f;
    Ucoef[gate][comp] = sgn * tr * cs;
  }
  __syncthreads();

  // phase 1: evolution, 256 threads = 16 columns x 16 amplitudes
  const int col = tid >> 4, amp = tid & 15;
  float re = (amp == col) ? 1.f : 0.f, im = 0.f;
#pragma unroll
  for (int layer = 0; layer < NLAYERS; ++layer) {
#pragma unroll
    for (int q = 0; q < NQ; ++q) {
      const int gate = layer * NQ + q;
      const int bit = 8 >> q;
      const bool lo = !(amp & bit);
      const float cr1 = lo ? Ucoef[gate][0] : Ucoef[gate][6];
      const float ci1 = lo ? Ucoef[gate][1] : Ucoef[gate][7];
      const float cr2 = lo ? Ucoef[gate][2] : Ucoef[gate][4];
      const float ci2 = lo ? Ucoef[gate][3] : Ucoef[gate][5];
      const float pr = __shfl_xor(re, bit);
      const float pi = __shfl_xor(im, bit);
      const float mr = re, mi = im;
      re = cr1 * mr - ci1 * mi + cr2 * pr - ci2 * pi;
      im = cr1 * mi + ci1 * mr + cr2 * pi + ci2 * pr;
    }
#pragma unroll
    for (int q = 0; q < NQ - 1; ++q) {
      const int cb = 8 >> q, tb = 4 >> q;
      const float pr = __shfl_xor(re, tb);
      const float pi = __shfl_xor(im, tb);
      if (amp & cb) { re = pr; im = pi; }
    }
  }
  Ur[amp][col] = re;
  Ui[amp][col] = im;
  __syncthreads();

  // A_q[i][j] = sum_k (+-1) * (Ur[k][i]Ur[k][j] + Ui[k][i]Ui[k][j])
  for (int e = tid; e < 4 * 16 * 16; e += blockDim.x) {
    const int q = e >> 8, i = (e >> 4) & 15, j = e & 15;
    float s = 0.f;
    for (int k = 0; k < 16; ++k) {
      const float d = ((k >> (3 - q)) & 1) ? -1.f : 1.f;
      s += d * (Ur[k][i] * Ur[k][j] + Ui[k][i] * Ui[k][j]);
    }
    A[q][i][j] = s;
  }
  // Wc[o][q] = Wout[o]·Wq2c[:,q];  g_off[o] = Wout[o]·bq2c + bout[o]
  if (tid < 12) {
    const int o = tid >> 2, q = tid & 3;
    float s = 0.f;
    for (int h = 0; h < 64; ++h) s += Wout[o * 64 + h] * Wq2c[h * 4 + q];
    Wc[o][q] = s;
  }
  if (tid < 3) {
    float s = bout[tid];
    for (int h = 0; h < 64; ++h) s += Wout[tid * 64 + h] * bq2c[h];
    g_off[tid] = s;
  }
  __syncthreads();

  // C[o][t] = (1/16) sum_i (-1)^{popc(i&zmask)} G_o[i][i^xmask]
  for (int e = tid; e < 243; e += blockDim.x) {
    const int o = e / 81, t = e % 81;
    const int tv0 = t / 27, tv1 = (t / 9) % 3, tv2 = (t / 3) % 3, tv3 = t % 3;
    const int tv[4] = {tv0, tv1, tv2, tv3};
    int xmask = 0, zmask = 0;
    for (int q = 0; q < 4; ++q) {
      const int b = 8 >> q;
      if (tv[q] == 2) xmask |= b;
      else if (tv[q] == 1) zmask |= b;
    }
    float s = 0.f;
    for (int i = 0; i < 16; ++i) {
      const int j = i ^ xmask;
      const float sgn = (__popc(i & zmask) & 1) ? -1.f : 1.f;
      const float g = Wc[o][0] * A[0][i][j] + Wc[o][1] * A[1][i][j] +
                      Wc[o][2] * A[2][i][j] + Wc[o][3] * A[3][i][j];
      s += sgn * g;
    }
    const float val = s * 0.0625f;
    if (o == 0) g_C01[2 * t] = val;
    else if (o == 1) g_C01[2 * t + 1] = val;
    else g_C2[t] = val;
  }
}

__device__ __forceinline__ float fast_tanh(float v) {
  const float e = __expf(2.f * v);
  return 1.f - 2.f * __builtin_amdgcn_rcpf(e + 1.f);
}

// ---- R3-verified building blocks, factored ----

__device__ __forceinline__ void load_x_group(const float* __restrict__ x,
                                             int wbase, int lane, int N,
                                             float4 xr[5]) {
  const float4* x4 = reinterpret_cast<const float4*>(x);
  const size_t max4 = (size_t)N * 5 - 1;
  const size_t base4 = (size_t)wbase * 5;
#pragma unroll
  for (int i = 0; i < 5; ++i) {
    size_t gi = base4 + (size_t)(i * 64 + lane);
    xr[i] = x4[gi <= max4 ? gi : max4];
  }
}

__device__ __forceinline__ void stage_x(float* ws, int lane, const float4 xr[5]) {
  // 32 floats/element, XOR bank swizzle (R3 layout) -> needs 2048 floats/wave
#pragma unroll
  for (int i = 0; i < 5; ++i) {
    const int m = i * 64 + lane;
    const int el = m / 5, ch = m % 5;
    *(float4*)&ws[el * 32 + ((ch * 4) ^ ((el & 7) << 2))] = xr[i];
  }
  const float4 bias4 = {1.f, 0.f, 0.f, 0.f};  // k==20 bias multiplier
  const float4 z4 = {0.f, 0.f, 0.f, 0.f};
  const int sw = (lane & 7) << 2;
  *(float4*)&ws[lane * 32 + ((5 * 4) ^ sw)] = bias4;
  *(float4*)&ws[lane * 32 + ((6 * 4) ^ sw)] = z4;
  *(float4*)&ws[lane * 32 + ((7 * 4) ^ sw)] = z4;
}

__device__ __forceinline__ f32x4 compute_group(const float* ws, int g, int cc,
                                               const bf16x8 Aemb[4],
                                               const bf16x8 A2[2]) {
  const f32x4 zero4 = {0.f, 0.f, 0.f, 0.f};
  f32x4 av = zero4;
#pragma unroll
  for (int rt = 0; rt < 4; ++rt) {
    const int el = rt * 16 + cc;
    const int sw = (el & 7) << 2;
    const float4 u0 = *(const float4*)&ws[el * 32 + ((g * 8 + 0) ^ sw)];
    const float4 u1 = *(const float4*)&ws[el * 32 + ((g * 8 + 4) ^ sw)];
    bf16x8 B;
    B[0] = (__bf16)u0.x; B[1] = (__bf16)u0.y; B[2] = (__bf16)u0.z; B[3] = (__bf16)u0.w;
    B[4] = (__bf16)u1.x; B[5] = (__bf16)u1.y; B[6] = (__bf16)u1.z; B[7] = (__bf16)u1.w;

    const f32x4 acc0 = __builtin_amdgcn_mfma_f32_16x16x32_bf16(Aemb[0], B, zero4, 0, 0, 0);
    const f32x4 acc1 = __builtin_amdgcn_mfma_f32_16x16x32_bf16(Aemb[1], B, zero4, 0, 0, 0);
    const f32x4 acc2 = __builtin_amdgcn_mfma_f32_16x16x32_bf16(Aemb[2], B, zero4, 0, 0, 0);
    const f32x4 acc3 = __builtin_amdgcn_mfma_f32_16x16x32_bf16(Aemb[3], B, zero4, 0, 0, 0);

    bf16x8 P0, P1;
#pragma unroll
    for (int j = 0; j < 8; ++j) {
      P0[j] = (__bf16)fmaxf(((j >> 2) ? acc1 : acc0)[j & 3], 0.f);
      P1[j] = (__bf16)fmaxf(((j >> 2) ? acc3 : acc2)[j & 3], 0.f);
    }
    f32x4 a2 = __builtin_amdgcn_mfma_f32_16x16x32_bf16(A2[0], P0, zero4, 0, 0, 0);
    a2 = __builtin_amdgcn_mfma_f32_16x16x32_bf16(A2[1], P1, a2, 0, 0, 0);

    if (g == rt) av = a2;  // lane owns element wbase + lane
  }
  return av;
}

__device__ __forceinline__ void tail_store(f32x4 av, const float* __restrict__ bc2q,
                                           float* __restrict__ out, int eo, int N) {
  const float a0 = fast_tanh(av[0] + bc2q[0]);
  const float a1 = fast_tanh(av[1] + bc2q[1]);
  const float a2v = fast_tanh(av[2] + bc2q[2]);
  const float a3 = fast_tanh(av[3] + bc2q[3]);

  const float f0v[3] = {1.f, __cosf(a0), __sinf(a0)};
  const float f1v[3] = {1.f, __cosf(a1), __sinf(a1)};
  const float f2v[3] = {1.f, __cosf(a2v), __sinf(a2v)};
  const float f3v[3] = {1.f, __cosf(a3), __sinf(a3)};

  float T23[9];
#pragma unroll
  for (int i2 = 0; i2 < 3; ++i2)
#pragma unroll
    for (int i3 = 0; i3 < 3; ++i3) T23[i2 * 3 + i3] = f2v[i2] * f3v[i3];
  float T[27];
#pragma unroll
  for (int i1 = 0; i1 < 3; ++i1)
#pragma unroll
    for (int k = 0; k < 9; ++k) T[i1 * 9 + k] = f1v[i1] * T23[k];

  // y0,y1 packed (v_pk_fma_f32), y2 scalar
  f32x2 y01 = {g_off[0], g_off[1]};
  float y2 = g_off[2];
#pragma unroll
  for (int i0 = 0; i0 < 3; ++i0) {
    f32x2 s01 = {0.f, 0.f};
    float s2 = 0.f;
#pragma unroll
    for (int k = 0; k < 27; ++k) {
      const float tv = T[k];
      const f32x2 c01 = *reinterpret_cast<const f32x2*>(&g_C01[2 * (i0 * 27 + k)]);
      s01 += c01 * tv;
      s2 = fmaf(g_C2[i0 * 27 + k], tv, s2);
    }
    y01 += s01 * f0v[i0];
    y2 = fmaf(f0v[i0], s2, y2);
  }

  if (eo < N) {
    out[eo * 3 + 0] = y01[0];
    out[eo * 3 + 1] = y01[1];
    out[eo * 3 + 2] = y2;
  }
}

// One wave = 128 elements as TWO pipelined 64-element groups.
// Group-1 x loads issue before group-0's MFMA phase (latency hidden);
// weight fragments built once per wave (amortized 2x). Same LDS slot reused
// via in-wave DS ordering (no barriers).
// D-layout (m89): col = lane&15, row = (lane>>4)*4 + reg.
__global__ __launch_bounds__(256, 4) void fused_kernel(
    const float* __restrict__ x,
    const float* __restrict__ Wemb,
    const float* __restrict__ bemb,
    const float* __restrict__ Wc2q,
    const float* __restrict__ bc2q,
    float* __restrict__ out, int N) {
  // 2048 floats per wave slot (32-float stride x 64 elements) — R6's bug was 1280 here.
  __shared__ __attribute__((aligned(16))) float smem[4][2048];  // 32 KB

  const int lane = threadIdx.x & 63;
  const int warp = threadIdx.x >> 6;
  const int wbase0 = (int)((blockIdx.x * 4 + warp) << 7);  // 128 elems/wave
  if (wbase0 >= N) return;
  const int wbase1 = wbase0 + 64;
  const int g = lane >> 4;    // k-group / D row-group
  const int cc = lane & 15;   // A row / B,D col
  float* ws = &smem[warp][0];

  // ---- group-0 x loads ----
  float4 xr0[5];
  load_x_group(x, wbase0, lane, N, xr0);

  // ---- weight fragments, built once (bias folded at k==20) ----
  bf16x8 Aemb[4];
#pragma unroll
  for (int ht = 0; ht < 4; ++ht) {
    const int h = ht * 16 + cc;
    const float* wr = Wemb + h * 20;
    float t0 = 0.f, t1 = 0.f, t2 = 0.f, t3 = 0.f, t4 = 0.f, t5 = 0.f, t6 = 0.f, t7 = 0.f;
    if (g < 2) {
      const float4 v0 = *(const float4*)(wr + g * 8);
      const float4 v1 = *(const float4*)(wr + g * 8 + 4);
      t0 = v0.x; t1 = v0.y; t2 = v0.z; t3 = v0.w;
      t4 = v1.x; t5 = v1.y; t6 = v1.z; t7 = v1.w;
    } else if (g == 2) {
      const float4 v0 = *(const float4*)(wr + 16);
      t0 = v0.x; t1 = v0.y; t2 = v0.z; t3 = v0.w;
      t4 = bemb[h];  // k==20 bias slot
    }
    Aemb[ht][0] = (__bf16)t0; Aemb[ht][1] = (__bf16)t1;
    Aemb[ht][2] = (__bf16)t2; Aemb[ht][3] = (__bf16)t3;
    Aemb[ht][4] = (__bf16)t4; Aemb[ht][5] = (__bf16)t5;
    Aemb[ht][6] = (__bf16)t6; Aemb[ht][7] = (__bf16)t7;
  }

  bf16x8 A2[2];
#pragma unroll
  for (int t = 0; t < 2; ++t) {
#pragma unroll
    for (int j = 0; j < 8; ++j) {
      const int mu = t * 32 + ((j >> 2) << 4) + (g << 2) + (j & 3);
      A2[t][j] = (__bf16)Wc2q[(cc & 3) * 64 + mu];
    }
  }

  // ---- stage group 0; issue group-1 loads (overlap with group-0 compute) ----
  stage_x(ws, lane, xr0);

  float4 xr1[5];
  const bool has1 = (wbase1 < N);
  if (has1) load_x_group(x, wbase1, lane, N, xr1);

  // ---- group 0: MFMA compute (group-1 loads in flight underneath) ----
  const f32x4 av0 = compute_group(ws, g, cc, Aemb, A2);

  if (has1) {
    // group-0 LDS reads are done (in-wave ordering) -> overwrite slot.
    // xr1 registers die here, before the register-heavy tail.
    stage_x(ws, lane, xr1);
    tail_store(av0, bc2q, out, wbase0 + lane, N);
    const f32x4 av1 = compute_group(ws, g, cc, Aemb, A2);
    tail_store(av1, bc2q, out, wbase1 + lane, N);
  } else {
    tail_store(av0, bc2q, out, wbase0 + lane, N);
  }
}

extern "C" void kernel_launch(void* const* d_in, const int* in_sizes, int n_in,
                              void* d_out, int out_size, void* d_ws, size_t ws_size,
                              hipStream_t stream) {
  const float* x    = (const float*)d_in[0];
  const float* Wemb = (const float*)d_in[1];
  const float* bemb = (const float*)d_in[2];
  const float* Wc2q = (const float*)d_in[3];
  const float* bc2q = (const float*)d_in[4];
  const float* qw   = (const float*)d_in[5];
  const float* Wq2c = (const float*)d_in[6];
  const float* bq2c = (const float*)d_in[7];
  const float* Wout = (const float*)d_in[8];
  const float* bout = (const float*)d_in[9];
  float* out = (float*)d_out;

  const int N = in_sizes[0] / 20;  // B*S = 262144

  hipLaunchKernelGGL(precompute_kernel, dim3(1), dim3(256), 0, stream,
                     qw, Wq2c, bq2c, Wout, bout);
  hipLaunchKernelGGL(fused_kernel, dim3((N + 511) / 512), dim3(256), 0, stream,
                     x, Wemb, bemb, Wc2q, bc2q, out, N);
}

// Round 8
// 20.673 us; speedup vs baseline: 1.2976x; 1.2976x over previous
//
#include <hip/hip_runtime.h>

typedef __bf16 bf16x8 __attribute__((ext_vector_type(8)));
typedef float f32x4 __attribute__((ext_vector_type(4)));
typedef float f32x2 __attribute__((ext_vector_type(2)));

// coords_o = sum_{t in {I,cos,sin}^4} C_o[t] * prod_q f_{t_q}(a_q) + c_o
// Packed: g_C01[2t+{0,1}] = C_{0,1}[t]; g_C2[t] = C_2[t]; g_off = offsets.
__device__ __attribute__((aligned(16))) float g_C01[162];
__device__ float g_C2[81];
__device__ float g_off[3];

#define NQ 4
#define NLAYERS 2

__global__ __launch_bounds__(256) void precompute_kernel(
    const float* __restrict__ qw,
    const float* __restrict__ Wq2c,
    const float* __restrict__ bq2c,
    const float* __restrict__ Wout,
    const float* __restrict__ bout) {
  __shared__ float Ucoef[8][8];  // [gate][u00r,u00i,u01r,u01i,u10r,u10i,u11r,u11i]
  __shared__ float Ur[16][16];   // Ur[amp][col] = Re <amp|U|col>
  __shared__ float Ui[16][16];
  __shared__ float A[4][16][16];
  __shared__ float Wc[3][4];
  const int tid = threadIdx.x;

  // phase 0: all 8 gates' 2x2 unitary entries, 64 threads in parallel
  if (tid < 64) {
    const int gate = tid >> 3, comp = tid & 7;
    const float phi   = qw[gate * 3 + 0];
    const float theta = qw[gate * 3 + 1];
    const float omega = qw[gate * 3 + 2];
    const float cs = (comp == 2 || comp == 3 || comp == 4 || comp == 5)
                         ? __sinf(0.5f * theta)    // st
                         : __cosf(0.5f * theta);   // ct
    const float ang = (comp == 2 || comp == 3 || comp == 4 || comp == 5)
                          ? -0.5f * (phi - omega)  // am
                          : -0.5f * (phi + omega); // ap
    const float tr = ((comp & 1) == 0) ? __cosf(ang) : __sinf(ang);
    // signs: u01r = -emr*st (comp2), u11i = -epi*ct (comp7)
    const float sgn = (comp == 2 || comp == 7) ? -1.f : 1.f;
    Ucoef[gate][comp] = sgn * tr * cs;
  }
  __syncthreads();

  // phase 1: evolution, 256 threads = 16 columns x 16 amplitudes
  const int col = tid >> 4, amp = tid & 15;
  float re = (amp == col) ? 1.f : 0.f, im = 0.f;
#pragma unroll
  for (int layer = 0; layer < NLAYERS; ++layer) {
#pragma unroll
    for (int q = 0; q < NQ; ++q) {
      const int gate = layer * NQ + q;
      const int bit = 8 >> q;
      const bool lo = !(amp & bit);
      const float cr1 = lo ? Ucoef[gate][0] : Ucoef[gate][6];
      const float ci1 = lo ? Ucoef[gate][1] : Ucoef[gate][7];
      const float cr2 = lo ? Ucoef[gate][2] : Ucoef[gate][4];
      const float ci2 = lo ? Ucoef[gate][3] : Ucoef[gate][5];
      const float pr = __shfl_xor(re, bit);
      const float pi = __shfl_xor(im, bit);
      const float mr = re, mi = im;
      re = cr1 * mr - ci1 * mi + cr2 * pr - ci2 * pi;
      im = cr1 * mi + ci1 * mr + cr2 * pi + ci2 * pr;
    }
#pragma unroll
    for (int q = 0; q < NQ - 1; ++q) {
      const int cb = 8 >> q, tb = 4 >> q;
      const float pr = __shfl_xor(re, tb);
      const float pi = __shfl_xor(im, tb);
      if (amp & cb) { re = pr; im = pi; }
    }
  }
  Ur[amp][col] = re;
  Ui[amp][col] = im;
  __syncthreads();

  // A_q[i][j] = sum_k (+-1) * (Ur[k][i]Ur[k][j] + Ui[k][i]Ui[k][j])
  for (int e = tid; e < 4 * 16 * 16; e += blockDim.x) {
    const int q = e >> 8, i = (e >> 4) & 15, j = e & 15;
    float s = 0.f;
    for (int k = 0; k < 16; ++k) {
      const float d = ((k >> (3 - q)) & 1) ? -1.f : 1.f;
      s += d * (Ur[k][i] * Ur[k][j] + Ui[k][i] * Ui[k][j]);
    }
    A[q][i][j] = s;
  }
  // Wc[o][q] = Wout[o]·Wq2c[:,q];  g_off[o] = Wout[o]·bq2c + bout[o]
  if (tid < 12) {
    const int o = tid >> 2, q = tid & 3;
    float s = 0.f;
    for (int h = 0; h < 64; ++h) s += Wout[o * 64 + h] * Wq2c[h * 4 + q];
    Wc[o][q] = s;
  }
  if (tid < 3) {
    float s = bout[tid];
    for (int h = 0; h < 64; ++h) s += Wout[tid * 64 + h] * bq2c[h];
    g_off[tid] = s;
  }
  __syncthreads();

  // C[o][t] = (1/16) sum_i (-1)^{popc(i&zmask)} G_o[i][i^xmask]
  for (int e = tid; e < 243; e += blockDim.x) {
    const int o = e / 81, t = e % 81;
    const int tv0 = t / 27, tv1 = (t / 9) % 3, tv2 = (t / 3) % 3, tv3 = t % 3;
    const int tv[4] = {tv0, tv1, tv2, tv3};
    int xmask = 0, zmask = 0;
    for (int q = 0; q < 4; ++q) {
      const int b = 8 >> q;
      if (tv[q] == 2) xmask |= b;
      else if (tv[q] == 1) zmask |= b;
    }
    float s = 0.f;
    for (int i = 0; i < 16; ++i) {
      const int j = i ^ xmask;
      const float sgn = (__popc(i & zmask) & 1) ? -1.f : 1.f;
      const float g = Wc[o][0] * A[0][i][j] + Wc[o][1] * A[1][i][j] +
                      Wc[o][2] * A[2][i][j] + Wc[o][3] * A[3][i][j];
      s += sgn * g;
    }
    const float val = s * 0.0625f;
    if (o == 0) g_C01[2 * t] = val;
    else if (o == 1) g_C01[2 * t + 1] = val;
    else g_C2[t] = val;
  }
}

__device__ __forceinline__ float fast_tanh(float v) {
  const float e = __expf(2.f * v);
  return 1.f - 2.f * __builtin_amdgcn_rcpf(e + 1.f);
}

// One wave = 64 elements, processed as 4 MFMA tiles of 16.
// Embed GEMM: h^T[64h][16elem] = Wemb(A) * x^T(B), K=32 (20 dims + bias slot).
// c2q GEMM: a[16q'][16elem] = Wc2q-replicated(A2) * relu(h^T)(B2), K=64.
// D-layout (m89): col = lane&15, row = (lane>>4)*4 + reg.
__global__ __launch_bounds__(256, 4) void fused_kernel(
    const float* __restrict__ x,
    const float* __restrict__ Wemb,
    const float* __restrict__ bemb,
    const float* __restrict__ Wc2q,
    const float* __restrict__ bc2q,
    float* __restrict__ out, int N) {
  __shared__ float xs[4][1280];  // [wave][64 elems x 20 dims], 20 KB

  const int tid = blockIdx.x * 256 + threadIdx.x;
  const int lane = threadIdx.x & 63;
  const int warp = threadIdx.x >> 6;
  const int wbase = (tid >> 6) << 6;
  if (wbase >= N) return;
  const int g = lane >> 4;    // k-group / D row-group
  const int cc = lane & 15;   // A row / B,D col

  const f32x4 zero4 = {0.f, 0.f, 0.f, 0.f};

  // ---- coalesced x stage: 5 x float4 per lane, wave-private LDS slot ----
  {
    const float4* x4 = reinterpret_cast<const float4*>(x);
    float4* ls4 = reinterpret_cast<float4*>(&xs[warp][0]);
    const size_t base4 = (size_t)wbase * 5;
    const size_t max4 = (size_t)N * 5 - 1;
#pragma unroll
    for (int i = 0; i < 5; ++i) {
      size_t gi = base4 + (size_t)(i * 64 + lane);
      ls4[i * 64 + lane] = x4[gi <= max4 ? gi : max4];
    }
  }

  // ---- one-time: Wemb A-fragments (4 h-tiles), bias folded at k==20 ----
  bf16x8 Aemb[4];
#pragma unroll
  for (int ht = 0; ht < 4; ++ht) {
    const int h = ht * 16 + cc;
    const float* wr = Wemb + h * 20;
    float t0 = 0.f, t1 = 0.f, t2 = 0.f, t3 = 0.f, t4 = 0.f, t5 = 0.f, t6 = 0.f, t7 = 0.f;
    if (g < 2) {
      const float4 v0 = *(const float4*)(wr + g * 8);
      const float4 v1 = *(const float4*)(wr + g * 8 + 4);
      t0 = v0.x; t1 = v0.y; t2 = v0.z; t3 = v0.w;
      t4 = v1.x; t5 = v1.y; t6 = v1.z; t7 = v1.w;
    } else if (g == 2) {
      const float4 v0 = *(const float4*)(wr + 16);
      t0 = v0.x; t1 = v0.y; t2 = v0.z; t3 = v0.w;
      t4 = bemb[h];  // k==20 bias slot
    }
    Aemb[ht][0] = (__bf16)t0; Aemb[ht][1] = (__bf16)t1;
    Aemb[ht][2] = (__bf16)t2; Aemb[ht][3] = (__bf16)t3;
    Aemb[ht][4] = (__bf16)t4; Aemb[ht][5] = (__bf16)t5;
    Aemb[ht][6] = (__bf16)t6; Aemb[ht][7] = (__bf16)t7;
  }

  // ---- one-time: Wc2q A2-fragments (q replicated over all 16 rows) ----
  bf16x8 A2[2];
#pragma unroll
  for (int t = 0; t < 2; ++t) {
#pragma unroll
    for (int j = 0; j < 8; ++j) {
      const int mu = t * 32 + ((j >> 2) << 4) + (g << 2) + (j & 3);
      A2[t][j] = (__bf16)Wc2q[(cc & 3) * 64 + mu];
    }
  }

  // ---- per-tile: embed MFMA + c2q MFMA; keep own tile's angles ----
  f32x4 av = zero4;
#pragma unroll
  for (int rt = 0; rt < 4; ++rt) {
    const int el = rt * 16 + cc;
    const float* ep = &xs[warp][el * 20];
    float t0 = 0.f, t1 = 0.f, t2 = 0.f, t3 = 0.f, t4 = 0.f, t5 = 0.f, t6 = 0.f, t7 = 0.f;
    if (g < 2) {
      const float4 v0 = *(const float4*)(ep + g * 8);
      const float4 v1 = *(const float4*)(ep + g * 8 + 4);
      t0 = v0.x; t1 = v0.y; t2 = v0.z; t3 = v0.w;
      t4 = v1.x; t5 = v1.y; t6 = v1.z; t7 = v1.w;
    } else if (g == 2) {
      const float4 v0 = *(const float4*)(ep + 16);
      t0 = v0.x; t1 = v0.y; t2 = v0.z; t3 = v0.w;
      t4 = 1.f;  // bias multiplier at k==20
    }
    bf16x8 B;
    B[0] = (__bf16)t0; B[1] = (__bf16)t1; B[2] = (__bf16)t2; B[3] = (__bf16)t3;
    B[4] = (__bf16)t4; B[5] = (__bf16)t5; B[6] = (__bf16)t6; B[7] = (__bf16)t7;

    const f32x4 acc0 = __builtin_amdgcn_mfma_f32_16x16x32_bf16(Aemb[0], B, zero4, 0, 0, 0);
    const f32x4 acc1 = __builtin_amdgcn_mfma_f32_16x16x32_bf16(Aemb[1], B, zero4, 0, 0, 0);
    const f32x4 acc2 = __builtin_amdgcn_mfma_f32_16x16x32_bf16(Aemb[2], B, zero4, 0, 0, 0);
    const f32x4 acc3 = __builtin_amdgcn_mfma_f32_16x16x32_bf16(Aemb[3], B, zero4, 0, 0, 0);

    bf16x8 P0, P1;
#pragma unroll
    for (int j = 0; j < 8; ++j) {
      P0[j] = (__bf16)fmaxf(((j >> 2) ? acc1 : acc0)[j & 3], 0.f);
      P1[j] = (__bf16)fmaxf(((j >> 2) ? acc3 : acc2)[j & 3], 0.f);
    }
    f32x4 a2 = __builtin_amdgcn_mfma_f32_16x16x32_bf16(A2[0], P0, zero4, 0, 0, 0);
    a2 = __builtin_amdgcn_mfma_f32_16x16x32_bf16(A2[1], P1, a2, 0, 0, 0);

    if (g == rt) av = a2;  // lane owns element wbase + lane
  }

  // ---- quantum closed form per owned element ----
  const float a0 = fast_tanh(av[0] + bc2q[0]);
  const float a1 = fast_tanh(av[1] + bc2q[1]);
  const float a2v = fast_tanh(av[2] + bc2q[2]);
  const float a3 = fast_tanh(av[3] + bc2q[3]);

  const float f0v[3] = {1.f, __cosf(a0), __sinf(a0)};
  const float f1v[3] = {1.f, __cosf(a1), __sinf(a1)};
  const float f2v[3] = {1.f, __cosf(a2v), __sinf(a2v)};
  const float f3v[3] = {1.f, __cosf(a3), __sinf(a3)};

  float T23[9];
#pragma unroll
  for (int i2 = 0; i2 < 3; ++i2)
#pragma unroll
    for (int i3 = 0; i3 < 3; ++i3) T23[i2 * 3 + i3] = f2v[i2] * f3v[i3];
  float T[27];
#pragma unroll
  for (int i1 = 0; i1 < 3; ++i1)
#pragma unroll
    for (int k = 0; k < 9; ++k) T[i1 * 9 + k] = f1v[i1] * T23[k];

  // y0,y1 packed (v_pk_fma_f32), y2 scalar
  f32x2 y01 = {g_off[0], g_off[1]};
  float y2 = g_off[2];
#pragma unroll
  for (int i0 = 0; i0 < 3; ++i0) {
    f32x2 s01 = {0.f, 0.f};
    float s2 = 0.f;
#pragma unroll
    for (int k = 0; k < 27; ++k) {
      const float tv = T[k];
      const f32x2 c01 = *reinterpret_cast<const f32x2*>(&g_C01[2 * (i0 * 27 + k)]);
      s01 += c01 * tv;
      s2 = fmaf(g_C2[i0 * 27 + k], tv, s2);
    }
    y01 += s01 * f0v[i0];
    y2 = fmaf(f0v[i0], s2, y2);
  }

  const int eo = wbase + lane;
  if (eo < N) {
    out[eo * 3 + 0] = y01[0];
    out[eo * 3 + 1] = y01[1];
    out[eo * 3 + 2] = y2;
  }
}

extern "C" void kernel_launch(void* const* d_in, const int* in_sizes, int n_in,
                              void* d_out, int out_size, void* d_ws, size_t ws_size,
                              hipStream_t stream) {
  const float* x    = (const float*)d_in[0];
  const float* Wemb = (const float*)d_in[1];
  const float* bemb = (const float*)d_in[2];
  const float* Wc2q = (const float*)d_in[3];
  const float* bc2q = (const float*)d_in[4];
  const float* qw   = (const float*)d_in[5];
  const float* Wq2c = (const float*)d_in[6];
  const float* bq2c = (const float*)d_in[7];
  const float* Wout = (const float*)d_in[8];
  const float* bout = (const float*)d_in[9];
  float* out = (float*)d_out;

  const int N = in_sizes[0] / 20;  // B*S = 262144

  hipLaunchKernelGGL(precompute_kernel, dim3(1), dim3(256), 0, stream,
                     qw, Wq2c, bq2c, Wout, bout);
  hipLaunchKernelGGL(fused_kernel, dim3((N + 255) / 256), dim3(256), 0, stream,
                     x, Wemb, bemb, Wc2q, bc2q, out, N);
}